// Round 8
// baseline (105.811 us; speedup 1.0000x reference)
//
#include <hip/hip_runtime.h>

typedef __attribute__((ext_vector_type(8))) short bf8;
typedef __attribute__((ext_vector_type(4))) float f4;
typedef unsigned short u16;

constexpr int B_ = 8, CIN = 256, CINT = 128, NN = 4096;
constexpr float L2E = 1.44269504088896f;

__device__ __forceinline__ u16 f2bf(float f) {
  unsigned int u = __builtin_bit_cast(unsigned int, f);
  u += 0x7FFFu + ((u >> 16) & 1u);   // round-to-nearest-even
  return (u16)(u >> 16);
}

__device__ __forceinline__ void glds16(const void* g, void* l) {
  __builtin_amdgcn_global_load_lds(
      (const __attribute__((address_space(1))) unsigned int*)g,
      (__attribute__((address_space(3))) unsigned int*)l, 16, 0, 0);
}

// pack two f32 -> one u32 of 2 bf16 (RTNE)
__device__ __forceinline__ int cvtpk(float lo, float hi) {
  int r;
  asm("v_cvt_pk_bf16_f32 %0, %1, %2" : "=v"(r) : "v"(lo), "v"(hi));
  return r;
}

// ---------------- prep: f32 weights -> bf16 [mat][128][256]
__global__ __launch_bounds__(256) void prep_kernel(
    const float* __restrict__ wth, const float* __restrict__ wph,
    const float* __restrict__ wg, u16* __restrict__ wbf)
{
  int i = blockIdx.x * 256 + threadIdx.x;          // 0..98303
  const float* src = (i < 32768) ? wth : (i < 65536) ? wph : wg;
  wbf[i] = f2bf(src[i & 32767]);
}

// ---------------- proj (unchanged from R7):
// theta [b][n][128] bf16 row-major.
// phiT  tiled [b][kt=n/32][r=n%32][128d], 16B chunks swizzled c16 ^= (r&7),
//       values pre-scaled by log2(e).
// gTt   tiled [b][kt=n/32][row=d>>1][(d&1)*32+k], 16B chunks c8 ^= (row&7).
__global__ __launch_bounds__(256) void proj_kernel(
    const float* __restrict__ x, const u16* __restrict__ wbf,
    const float* __restrict__ bth, const float* __restrict__ bph,
    const float* __restrict__ bg,
    u16* __restrict__ theta, u16* __restrict__ phiT, u16* __restrict__ gTt)
{
  const int b = blockIdx.y, n0 = blockIdx.x * 64;
  const int tid = threadIdx.x, w = tid >> 6, l = tid & 63;
  const int lr = l & 15, lg = l >> 4;
  __shared__ __align__(16) u16 sx[64 * 256];       // [n][c], swizzled, 32KB

  const float* xb = x + (size_t)b * CIN * NN + n0;
  #pragma unroll
  for (int pass = 0; pass < 8; ++pass) {
    const int cb = w * 8 + pass * 32;
    u16 tmp[8];
    #pragma unroll
    for (int i = 0; i < 8; ++i) tmp[i] = f2bf(xb[(size_t)(cb + i) * NN + l]);
    uint4 v;
    v.x = (unsigned)tmp[0] | ((unsigned)tmp[1] << 16);
    v.y = (unsigned)tmp[2] | ((unsigned)tmp[3] << 16);
    v.z = (unsigned)tmp[4] | ((unsigned)tmp[5] << 16);
    v.w = (unsigned)tmp[6] | ((unsigned)tmp[7] << 16);
    *(uint4*)&sx[l * 256 + (((w + pass * 4) ^ (l & 7)) << 3)] = v;
  }
  __syncthreads();

  #pragma unroll
  for (int dti = 0; dti < 6; ++dti) {
    const int dt = w * 6 + dti;
    const int mat = dt >> 3, d0 = (dt & 7) * 16;
    const float* Bv = (mat == 0) ? bth : (mat == 1) ? bph : bg;
    const u16* wrow = wbf + mat * 32768 + (size_t)(d0 + lr) * 256 + lg * 8;
    bf8 wf[8];
    #pragma unroll
    for (int ks = 0; ks < 8; ++ks) wf[ks] = *(const bf8*)(wrow + ks * 32);

    #pragma unroll
    for (int mt = 0; mt < 4; ++mt) {
      f4 acc = {0.f, 0.f, 0.f, 0.f};
      const int row = mt * 16 + lr;
      #pragma unroll
      for (int ks = 0; ks < 8; ++ks) {
        bf8 bx = *(const bf8*)&sx[row * 256 + (((ks * 4 + lg) ^ (lr & 7)) << 3)];
        acc = __builtin_amdgcn_mfma_f32_16x16x32_bf16(wf[ks], bx, acc, 0, 0, 0);
      }
      const int m = n0 + mt * 16 + lr;
      const int dlo = d0 + lg * 4;
      if (mat == 0) {
        ushort4 h4;
        h4.x = f2bf(acc[0] + Bv[dlo + 0]);
        h4.y = f2bf(acc[1] + Bv[dlo + 1]);
        h4.z = f2bf(acc[2] + Bv[dlo + 2]);
        h4.w = f2bf(acc[3] + Bv[dlo + 3]);
        *(ushort4*)&theta[((size_t)b * NN + m) * CINT + dlo] = h4;
      } else if (mat == 1) {
        const int kt = m >> 5, r32 = m & 31;
        ushort4 h4;
        h4.x = f2bf((acc[0] + Bv[dlo + 0]) * L2E);
        h4.y = f2bf((acc[1] + Bv[dlo + 1]) * L2E);
        h4.z = f2bf((acc[2] + Bv[dlo + 2]) * L2E);
        h4.w = f2bf((acc[3] + Bv[dlo + 3]) * L2E);
        *(ushort4*)&phiT[((size_t)(b * 128 + kt)) * 4096 + r32 * 128 +
                         ((((dlo >> 3) ^ (r32 & 7))) << 3) + (dlo & 7)] = h4;
      } else {
        const int kt = m >> 5, kk = m & 31;
        #pragma unroll
        for (int r = 0; r < 4; ++r) {
          const int d = dlo + r;
          const int grow = d >> 1;
          const int chunk = (((d & 1) * 4 + (kk >> 3)) ^ (grow & 7));
          gTt[((size_t)(b * 128 + kt)) * 4096 + grow * 64 + chunk * 8 + (kk & 7)]
              = f2bf(acc[r] + Bv[d]);
        }
      }
    }
  }
}

// ---------------- attn: 8 waves = 2 q-waves (64 q, qt=4) x 4 k-quarters; KT=32.
// 2-buffer glds16 pipeline per quarter; P in registers (cvt_pk + permlane).
__global__ __launch_bounds__(512, 2) void attn_kernel(
    const u16* __restrict__ theta, const u16* __restrict__ phiT,
    const u16* __restrict__ gTt, float* __restrict__ out)
{
  const int b  = blockIdx.y;
  const int t_ = threadIdx.x;
  const int w  = t_ >> 6;
  const int l  = t_ & 63;
  const int lr = l & 15, lg = l >> 4;
  const int qs = w & 1, h = w >> 1;          // q-wave, k-quarter
  const int q0 = blockIdx.x * 128 + qs * 64;

  // LDS: phi 4h x 2buf x 8KB (0..64K) | g same (64K..128K) | combine reuse
  __shared__ __align__(16) char smem[135168];
  u16* sphi_b = (u16*)smem;
  u16* sg_b   = (u16*)(smem + 65536);

  const u16* th = theta + (size_t)b * NN * CINT;
  bf8 qf[4][4];
  #pragma unroll
  for (int qt = 0; qt < 4; ++qt)
    #pragma unroll
    for (int ds = 0; ds < 4; ++ds)
      qf[qt][ds] = *(const bf8*)(th + (size_t)(q0 + qt * 16 + lr) * CINT + ds * 32 + lg * 8);

  f4 y[4][8];
  #pragma unroll
  for (int qt = 0; qt < 4; ++qt)
    #pragma unroll
    for (int dt = 0; dt < 8; ++dt) y[qt][dt] = (f4){0.f, 0.f, 0.f, 0.f};
  float rs[4] = {0.f, 0.f, 0.f, 0.f};

  // sources: quarter h covers kt = h*32 .. h*32+31
  const char* psrc = (const char*)(phiT + (size_t)(b * 128 + h * 32) * 4096) +
                     qs * 4096 + l * 16;
  const char* gsrc = (const char*)(gTt + (size_t)(b * 128 + h * 32) * 4096) +
                     qs * 4096 + l * 16;

  #define STAGE(BUF, T)                                                    \
    {                                                                      \
      const char* sp = psrc + (size_t)(T) * 8192;                          \
      const char* sq = gsrc + (size_t)(T) * 8192;                          \
      char* lp = (char*)sphi_b + (h * 2 + (BUF)) * 8192 + qs * 4096;       \
      char* lq = (char*)sg_b + (h * 2 + (BUF)) * 8192 + qs * 4096;         \
      glds16(sp, lp);        glds16(sp + 1024, lp + 1024);                 \
      glds16(sp + 2048, lp + 2048); glds16(sp + 3072, lp + 3072);          \
      glds16(sq, lq);        glds16(sq + 1024, lq + 1024);                 \
      glds16(sq + 2048, lq + 2048); glds16(sq + 3072, lq + 3072);          \
    }

  STAGE(0, 0);
  asm volatile("s_waitcnt vmcnt(0)" ::: "memory");
  __builtin_amdgcn_s_barrier();
  __builtin_amdgcn_sched_barrier(0);

  int cur = 0;
  for (int t = 0; t < 32; ++t) {
    if (t < 31) STAGE(cur ^ 1, t + 1);

    const u16* PH = sphi_b + (h * 2 + cur) * 4096;
    const u16* GG = sg_b + (h * 2 + cur) * 4096;

    int pw0[4], pw1[4], pw2[4], pw3[4];

    // ---- QK^T st0 (k rows 0..15): A = phi, B = theta
    {
      f4 s[4];
      #pragma unroll
      for (int qt = 0; qt < 4; ++qt) s[qt] = (f4){0.f, 0.f, 0.f, 0.f};
      __builtin_amdgcn_s_setprio(1);
      #pragma unroll
      for (int ds = 0; ds < 4; ++ds) {
        bf8 af = *(const bf8*)(PH + lr * 128 + (((ds * 4 + lg) ^ (lr & 7)) << 3));
        #pragma unroll
        for (int qt = 0; qt < 4; ++qt)
          s[qt] = __builtin_amdgcn_mfma_f32_16x16x32_bf16(af, qf[qt][ds], s[qt], 0, 0, 0);
      }
      __builtin_amdgcn_s_setprio(0);
      #pragma unroll
      for (int qt = 0; qt < 4; ++qt) {
        float p0 = __builtin_amdgcn_exp2f(s[qt][0]);
        float p1 = __builtin_amdgcn_exp2f(s[qt][1]);
        float p2 = __builtin_amdgcn_exp2f(s[qt][2]);
        float p3 = __builtin_amdgcn_exp2f(s[qt][3]);
        rs[qt] += (p0 + p1) + (p2 + p3);
        pw0[qt] = cvtpk(p0, p1);
        pw1[qt] = cvtpk(p2, p3);
      }
    }
    // ---- QK^T st1 (k rows 16..31)
    {
      f4 s[4];
      #pragma unroll
      for (int qt = 0; qt < 4; ++qt) s[qt] = (f4){0.f, 0.f, 0.f, 0.f};
      __builtin_amdgcn_s_setprio(1);
      #pragma unroll
      for (int ds = 0; ds < 4; ++ds) {
        bf8 af = *(const bf8*)(PH + (16 + lr) * 128 + (((ds * 4 + lg) ^ (lr & 7)) << 3));
        #pragma unroll
        for (int qt = 0; qt < 4; ++qt)
          s[qt] = __builtin_amdgcn_mfma_f32_16x16x32_bf16(af, qf[qt][ds], s[qt], 0, 0, 0);
      }
      __builtin_amdgcn_s_setprio(0);
      #pragma unroll
      for (int qt = 0; qt < 4; ++qt) {
        float p0 = __builtin_amdgcn_exp2f(s[qt][0]);
        float p1 = __builtin_amdgcn_exp2f(s[qt][1]);
        float p2 = __builtin_amdgcn_exp2f(s[qt][2]);
        float p3 = __builtin_amdgcn_exp2f(s[qt][3]);
        rs[qt] += (p0 + p1) + (p2 + p3);
        pw2[qt] = cvtpk(p0, p1);
        pw3[qt] = cvtpk(p2, p3);
      }
    }

    // ---- in-register P fragments (verified R7 pattern)
    bf8 paf[4];
    #pragma unroll
    for (int qt = 0; qt < 4; ++qt) {
      int w0 = pw0[qt], w1 = pw1[qt], w2 = pw2[qt], w3 = pw3[qt];
      asm volatile("v_permlane32_swap_b32 %0, %1" : "+v"(w0), "+v"(w2));
      asm volatile("v_permlane16_swap_b32 %0, %1" : "+v"(w0), "+v"(w2));
      asm volatile("v_permlane32_swap_b32 %0, %1" : "+v"(w1), "+v"(w3));
      asm volatile("v_permlane16_swap_b32 %0, %1" : "+v"(w1), "+v"(w3));
      int pai[4] = {w0, w1, w2, w3};
      paf[qt] = __builtin_bit_cast(bf8, *(int4*)pai);
    }

    // ---- PV: A = P (q rows), B = g (d rows)
    __builtin_amdgcn_s_setprio(1);
    #pragma unroll
    for (int dt = 0; dt < 8; ++dt) {
      const int grow = dt * 8 + (lr >> 1);
      const int chunk = (((lr & 1) * 4 + lg) ^ (grow & 7));
      bf8 gf = *(const bf8*)(GG + grow * 64 + (chunk << 3));
      #pragma unroll
      for (int qt = 0; qt < 4; ++qt)
        y[qt][dt] = __builtin_amdgcn_mfma_f32_16x16x32_bf16(paf[qt], gf, y[qt][dt], 0, 0, 0);
    }
    __builtin_amdgcn_s_setprio(0);

    asm volatile("s_waitcnt vmcnt(0)" ::: "memory");
    __builtin_amdgcn_s_barrier();
    __builtin_amdgcn_sched_barrier(0);
    cur ^= 1;
  }

  // ---- per-lane k-reduce over lg, then 4-way quarter combine via LDS
  #pragma unroll
  for (int qt = 0; qt < 4; ++qt) {
    rs[qt] += __shfl_xor(rs[qt], 16);
    rs[qt] += __shfl_xor(rs[qt], 32);
  }
  __syncthreads();
  float* yc = (float*)smem;                 // 4 slots x 32KB
  float* rc = (float*)(smem + 131072);      // 4 slots x 256 f32

  if (h >= 2) {                             // h2 -> slot qs, h3 -> slot 2+qs
    const int slot = (h & 1) * 2 + qs;
    #pragma unroll
    for (int qt = 0; qt < 4; ++qt) {
      #pragma unroll
      for (int dt = 0; dt < 8; ++dt)
        *(f4*)&yc[slot * 8192 + (qt * 8 + dt) * 256 + l * 4] = y[qt][dt];
      rc[slot * 256 + qt * 64 + l] = rs[qt];
    }
  }
  __syncthreads();
  if (h < 2) {
    const int slot = h * 2 + qs;
    #pragma unroll
    for (int qt = 0; qt < 4; ++qt) {
      #pragma unroll
      for (int dt = 0; dt < 8; ++dt)
        y[qt][dt] += *(const f4*)&yc[slot * 8192 + (qt * 8 + dt) * 256 + l * 4];
      rs[qt] += rc[slot * 256 + qt * 64 + l];
    }
  }
  __syncthreads();
  if (h == 1) {
    #pragma unroll
    for (int qt = 0; qt < 4; ++qt) {
      #pragma unroll
      for (int dt = 0; dt < 8; ++dt)
        *(f4*)&yc[qs * 8192 + (qt * 8 + dt) * 256 + l * 4] = y[qt][dt];
      rc[qs * 256 + qt * 64 + l] = rs[qt];
    }
  }
  __syncthreads();
  if (h == 0) {
    #pragma unroll
    for (int qt = 0; qt < 4; ++qt) {
      #pragma unroll
      for (int dt = 0; dt < 8; ++dt)
        y[qt][dt] += *(const f4*)&yc[qs * 8192 + (qt * 8 + dt) * 256 + l * 4];
      rs[qt] += rc[qs * 256 + qt * 64 + l];
    }
    float* ob = out + (size_t)b * CINT * NN;
    #pragma unroll
    for (int qt = 0; qt < 4; ++qt) {
      f4 rsi;
      #pragma unroll
      for (int r = 0; r < 4; ++r)
        rsi[r] = 1.0f / __shfl(rs[qt], lg * 4 + r, 64);
      #pragma unroll
      for (int dt = 0; dt < 8; ++dt) {
        f4 v = y[qt][dt] * rsi;
        *(float4*)&ob[(size_t)(dt * 16 + lr) * NN + q0 + qt * 16 + lg * 4] = *(float4*)&v;
      }
    }
  }
}

extern "C" void kernel_launch(void* const* d_in, const int* in_sizes, int n_in,
                              void* d_out, int out_size, void* d_ws, size_t ws_size,
                              hipStream_t stream) {
  const float* x   = (const float*)d_in[0];
  const float* wth = (const float*)d_in[1];
  const float* bth = (const float*)d_in[2];
  const float* wph = (const float*)d_in[3];
  const float* bph = (const float*)d_in[4];
  const float* wg  = (const float*)d_in[5];
  const float* bg  = (const float*)d_in[6];
  float* out = (float*)d_out;

  u16* theta = (u16*)d_ws;
  u16* phiT  = theta + (size_t)B_ * NN * CINT;
  u16* gTt   = phiT  + (size_t)B_ * NN * CINT;
  u16* wbf   = gTt   + (size_t)B_ * NN * CINT;

  hipLaunchKernelGGL(prep_kernel, dim3(384), dim3(256), 0, stream, wth, wph, wg, wbf);
  hipLaunchKernelGGL(proj_kernel, dim3(64, 8), dim3(256), 0, stream,
                     x, wbf, bth, bph, bg, theta, phiT, gTt);
  hipLaunchKernelGGL(attn_kernel, dim3(32, 8), dim3(512), 0, stream,
                     theta, phiT, gTt, out);
}

// Round 9
// 105.747 us; speedup vs baseline: 1.0006x; 1.0006x over previous
//
#include <hip/hip_runtime.h>

typedef __attribute__((ext_vector_type(8))) short bf8;
typedef __attribute__((ext_vector_type(4))) float f4;
typedef unsigned short u16;

constexpr int B_ = 8, CIN = 256, CINT = 128, NN = 4096;
constexpr float L2E = 1.44269504088896f;

__device__ __forceinline__ u16 f2bf(float f) {
  unsigned int u = __builtin_bit_cast(unsigned int, f);
  u += 0x7FFFu + ((u >> 16) & 1u);   // round-to-nearest-even
  return (u16)(u >> 16);
}

__device__ __forceinline__ void glds16(const void* g, void* l) {
  __builtin_amdgcn_global_load_lds(
      (const __attribute__((address_space(1))) unsigned int*)g,
      (__attribute__((address_space(3))) unsigned int*)l, 16, 0, 0);
}

// pack two f32 -> one u32 of 2 bf16 (RTNE)
__device__ __forceinline__ int cvtpk(float lo, float hi) {
  int r;
  asm("v_cvt_pk_bf16_f32 %0, %1, %2" : "=v"(r) : "v"(lo), "v"(hi));
  return r;
}

// ---------------- prep: f32 weights -> bf16 [mat][128][256]
__global__ __launch_bounds__(256) void prep_kernel(
    const float* __restrict__ wth, const float* __restrict__ wph,
    const float* __restrict__ wg, u16* __restrict__ wbf)
{
  int i = blockIdx.x * 256 + threadIdx.x;          // 0..98303
  const float* src = (i < 32768) ? wth : (i < 65536) ? wph : wg;
  wbf[i] = f2bf(src[i & 32767]);
}

// ---------------- proj (unchanged):
// theta [b][n][128] bf16 row-major.
// phiT  tiled [b][kt=n/32][r=n%32][128d], 16B chunks swizzled c16 ^= (r&7),
//       values pre-scaled by log2(e).
// gTt   tiled [b][kt=n/32][row=d>>1][(d&1)*32+k], 16B chunks c8 ^= (row&7).
__global__ __launch_bounds__(256) void proj_kernel(
    const float* __restrict__ x, const u16* __restrict__ wbf,
    const float* __restrict__ bth, const float* __restrict__ bph,
    const float* __restrict__ bg,
    u16* __restrict__ theta, u16* __restrict__ phiT, u16* __restrict__ gTt)
{
  const int b = blockIdx.y, n0 = blockIdx.x * 64;
  const int tid = threadIdx.x, w = tid >> 6, l = tid & 63;
  const int lr = l & 15, lg = l >> 4;
  __shared__ __align__(16) u16 sx[64 * 256];       // [n][c], swizzled, 32KB

  const float* xb = x + (size_t)b * CIN * NN + n0;
  #pragma unroll
  for (int pass = 0; pass < 8; ++pass) {
    const int cb = w * 8 + pass * 32;
    u16 tmp[8];
    #pragma unroll
    for (int i = 0; i < 8; ++i) tmp[i] = f2bf(xb[(size_t)(cb + i) * NN + l]);
    uint4 v;
    v.x = (unsigned)tmp[0] | ((unsigned)tmp[1] << 16);
    v.y = (unsigned)tmp[2] | ((unsigned)tmp[3] << 16);
    v.z = (unsigned)tmp[4] | ((unsigned)tmp[5] << 16);
    v.w = (unsigned)tmp[6] | ((unsigned)tmp[7] << 16);
    *(uint4*)&sx[l * 256 + (((w + pass * 4) ^ (l & 7)) << 3)] = v;
  }
  __syncthreads();

  #pragma unroll
  for (int dti = 0; dti < 6; ++dti) {
    const int dt = w * 6 + dti;
    const int mat = dt >> 3, d0 = (dt & 7) * 16;
    const float* Bv = (mat == 0) ? bth : (mat == 1) ? bph : bg;
    const u16* wrow = wbf + mat * 32768 + (size_t)(d0 + lr) * 256 + lg * 8;
    bf8 wf[8];
    #pragma unroll
    for (int ks = 0; ks < 8; ++ks) wf[ks] = *(const bf8*)(wrow + ks * 32);

    #pragma unroll
    for (int mt = 0; mt < 4; ++mt) {
      f4 acc = {0.f, 0.f, 0.f, 0.f};
      const int row = mt * 16 + lr;
      #pragma unroll
      for (int ks = 0; ks < 8; ++ks) {
        bf8 bx = *(const bf8*)&sx[row * 256 + (((ks * 4 + lg) ^ (lr & 7)) << 3)];
        acc = __builtin_amdgcn_mfma_f32_16x16x32_bf16(wf[ks], bx, acc, 0, 0, 0);
      }
      const int m = n0 + mt * 16 + lr;
      const int dlo = d0 + lg * 4;
      if (mat == 0) {
        ushort4 h4;
        h4.x = f2bf(acc[0] + Bv[dlo + 0]);
        h4.y = f2bf(acc[1] + Bv[dlo + 1]);
        h4.z = f2bf(acc[2] + Bv[dlo + 2]);
        h4.w = f2bf(acc[3] + Bv[dlo + 3]);
        *(ushort4*)&theta[((size_t)b * NN + m) * CINT + dlo] = h4;
      } else if (mat == 1) {
        const int kt = m >> 5, r32 = m & 31;
        ushort4 h4;
        h4.x = f2bf((acc[0] + Bv[dlo + 0]) * L2E);
        h4.y = f2bf((acc[1] + Bv[dlo + 1]) * L2E);
        h4.z = f2bf((acc[2] + Bv[dlo + 2]) * L2E);
        h4.w = f2bf((acc[3] + Bv[dlo + 3]) * L2E);
        *(ushort4*)&phiT[((size_t)(b * 128 + kt)) * 4096 + r32 * 128 +
                         ((((dlo >> 3) ^ (r32 & 7))) << 3) + (dlo & 7)] = h4;
      } else {
        const int kt = m >> 5, kk = m & 31;
        #pragma unroll
        for (int r = 0; r < 4; ++r) {
          const int d = dlo + r;
          const int grow = d >> 1;
          const int chunk = (((d & 1) * 4 + (kk >> 3)) ^ (grow & 7));
          gTt[((size_t)(b * 128 + kt)) * 4096 + grow * 64 + chunk * 8 + (kk & 7)]
              = f2bf(acc[r] + Bv[d]);
        }
      }
    }
  }
}

// ---------------- attn: XCD-pinned (batch = bid&7 -> all of a batch's blocks
// land on one XCD; its 2MB phi+g set becomes L2-resident).
// 8 waves = 2 q-waves (64 q, qt=4) x 4 k-quarters; KT=32; 2-buf glds16.
__global__ __launch_bounds__(512, 2) void attn_kernel(
    const u16* __restrict__ theta, const u16* __restrict__ phiT,
    const u16* __restrict__ gTt, float* __restrict__ out)
{
  const int bid = blockIdx.x;
  const int b   = bid & 7;          // XCD-pinned batch
  const int qtl = bid >> 3;         // q-tile 0..31
  const int t_ = threadIdx.x;
  const int w  = t_ >> 6;
  const int l  = t_ & 63;
  const int lr = l & 15, lg = l >> 4;
  const int qs = w & 1, h = w >> 1;          // q-wave, k-quarter
  const int q0 = qtl * 128 + qs * 64;

  // LDS: phi 4h x 2buf x 8KB (0..64K) | g same (64K..128K) | combine reuse
  __shared__ __align__(16) char smem[135168];
  u16* sphi_b = (u16*)smem;
  u16* sg_b   = (u16*)(smem + 65536);

  const u16* th = theta + (size_t)b * NN * CINT;
  bf8 qf[4][4];
  #pragma unroll
  for (int qt = 0; qt < 4; ++qt)
    #pragma unroll
    for (int ds = 0; ds < 4; ++ds)
      qf[qt][ds] = *(const bf8*)(th + (size_t)(q0 + qt * 16 + lr) * CINT + ds * 32 + lg * 8);

  f4 y[4][8];
  #pragma unroll
  for (int qt = 0; qt < 4; ++qt)
    #pragma unroll
    for (int dt = 0; dt < 8; ++dt) y[qt][dt] = (f4){0.f, 0.f, 0.f, 0.f};
  float rs[4] = {0.f, 0.f, 0.f, 0.f};

  // sources: quarter h covers kt = h*32 .. h*32+31
  const char* psrc = (const char*)(phiT + (size_t)(b * 128 + h * 32) * 4096) +
                     qs * 4096 + l * 16;
  const char* gsrc = (const char*)(gTt + (size_t)(b * 128 + h * 32) * 4096) +
                     qs * 4096 + l * 16;

  #define STAGE(BUF, T)                                                    \
    {                                                                      \
      const char* sp = psrc + (size_t)(T) * 8192;                          \
      const char* sq = gsrc + (size_t)(T) * 8192;                          \
      char* lp = (char*)sphi_b + (h * 2 + (BUF)) * 8192 + qs * 4096;       \
      char* lq = (char*)sg_b + (h * 2 + (BUF)) * 8192 + qs * 4096;         \
      glds16(sp, lp);        glds16(sp + 1024, lp + 1024);                 \
      glds16(sp + 2048, lp + 2048); glds16(sp + 3072, lp + 3072);          \
      glds16(sq, lq);        glds16(sq + 1024, lq + 1024);                 \
      glds16(sq + 2048, lq + 2048); glds16(sq + 3072, lq + 3072);          \
    }

  STAGE(0, 0);
  asm volatile("s_waitcnt vmcnt(0)" ::: "memory");
  __builtin_amdgcn_s_barrier();
  __builtin_amdgcn_sched_barrier(0);

  int cur = 0;
  for (int t = 0; t < 32; ++t) {
    if (t < 31) STAGE(cur ^ 1, t + 1);

    const u16* PH = sphi_b + (h * 2 + cur) * 4096;
    const u16* GG = sg_b + (h * 2 + cur) * 4096;

    int pw0[4], pw1[4], pw2[4], pw3[4];

    // ---- QK^T st0 (k rows 0..15): A = phi, B = theta
    {
      f4 s[4];
      #pragma unroll
      for (int qt = 0; qt < 4; ++qt) s[qt] = (f4){0.f, 0.f, 0.f, 0.f};
      __builtin_amdgcn_s_setprio(1);
      #pragma unroll
      for (int ds = 0; ds < 4; ++ds) {
        bf8 af = *(const bf8*)(PH + lr * 128 + (((ds * 4 + lg) ^ (lr & 7)) << 3));
        #pragma unroll
        for (int qt = 0; qt < 4; ++qt)
          s[qt] = __builtin_amdgcn_mfma_f32_16x16x32_bf16(af, qf[qt][ds], s[qt], 0, 0, 0);
      }
      __builtin_amdgcn_s_setprio(0);
      #pragma unroll
      for (int qt = 0; qt < 4; ++qt) {
        float p0 = __builtin_amdgcn_exp2f(s[qt][0]);
        float p1 = __builtin_amdgcn_exp2f(s[qt][1]);
        float p2 = __builtin_amdgcn_exp2f(s[qt][2]);
        float p3 = __builtin_amdgcn_exp2f(s[qt][3]);
        rs[qt] += (p0 + p1) + (p2 + p3);
        pw0[qt] = cvtpk(p0, p1);
        pw1[qt] = cvtpk(p2, p3);
      }
    }
    // ---- QK^T st1 (k rows 16..31)
    {
      f4 s[4];
      #pragma unroll
      for (int qt = 0; qt < 4; ++qt) s[qt] = (f4){0.f, 0.f, 0.f, 0.f};
      __builtin_amdgcn_s_setprio(1);
      #pragma unroll
      for (int ds = 0; ds < 4; ++ds) {
        bf8 af = *(const bf8*)(PH + (16 + lr) * 128 + (((ds * 4 + lg) ^ (lr & 7)) << 3));
        #pragma unroll
        for (int qt = 0; qt < 4; ++qt)
          s[qt] = __builtin_amdgcn_mfma_f32_16x16x32_bf16(af, qf[qt][ds], s[qt], 0, 0, 0);
      }
      __builtin_amdgcn_s_setprio(0);
      #pragma unroll
      for (int qt = 0; qt < 4; ++qt) {
        float p0 = __builtin_amdgcn_exp2f(s[qt][0]);
        float p1 = __builtin_amdgcn_exp2f(s[qt][1]);
        float p2 = __builtin_amdgcn_exp2f(s[qt][2]);
        float p3 = __builtin_amdgcn_exp2f(s[qt][3]);
        rs[qt] += (p0 + p1) + (p2 + p3);
        pw2[qt] = cvtpk(p0, p1);
        pw3[qt] = cvtpk(p2, p3);
      }
    }

    // ---- in-register P fragments (verified pattern)
    bf8 paf[4];
    #pragma unroll
    for (int qt = 0; qt < 4; ++qt) {
      int w0 = pw0[qt], w1 = pw1[qt], w2 = pw2[qt], w3 = pw3[qt];
      asm volatile("v_permlane32_swap_b32 %0, %1" : "+v"(w0), "+v"(w2));
      asm volatile("v_permlane16_swap_b32 %0, %1" : "+v"(w0), "+v"(w2));
      asm volatile("v_permlane32_swap_b32 %0, %1" : "+v"(w1), "+v"(w3));
      asm volatile("v_permlane16_swap_b32 %0, %1" : "+v"(w1), "+v"(w3));
      int pai[4] = {w0, w1, w2, w3};
      paf[qt] = __builtin_bit_cast(bf8, *(int4*)pai);
    }

    // ---- PV: A = P (q rows), B = g (d rows)
    __builtin_amdgcn_s_setprio(1);
    #pragma unroll
    for (int dt = 0; dt < 8; ++dt) {
      const int grow = dt * 8 + (lr >> 1);
      const int chunk = (((lr & 1) * 4 + lg) ^ (grow & 7));
      bf8 gf = *(const bf8*)(GG + grow * 64 + (chunk << 3));
      #pragma unroll
      for (int qt = 0; qt < 4; ++qt)
        y[qt][dt] = __builtin_amdgcn_mfma_f32_16x16x32_bf16(paf[qt], gf, y[qt][dt], 0, 0, 0);
    }
    __builtin_amdgcn_s_setprio(0);

    asm volatile("s_waitcnt vmcnt(0)" ::: "memory");
    __builtin_amdgcn_s_barrier();
    __builtin_amdgcn_sched_barrier(0);
    cur ^= 1;
  }

  // ---- per-lane k-reduce over lg, then 4-way quarter combine via LDS
  #pragma unroll
  for (int qt = 0; qt < 4; ++qt) {
    rs[qt] += __shfl_xor(rs[qt], 16);
    rs[qt] += __shfl_xor(rs[qt], 32);
  }
  __syncthreads();
  float* yc = (float*)smem;                 // 4 slots x 32KB
  float* rc = (float*)(smem + 131072);      // 4 slots x 256 f32

  if (h >= 2) {                             // h2 -> slot qs, h3 -> slot 2+qs
    const int slot = (h & 1) * 2 + qs;
    #pragma unroll
    for (int qt = 0; qt < 4; ++qt) {
      #pragma unroll
      for (int dt = 0; dt < 8; ++dt)
        *(f4*)&yc[slot * 8192 + (qt * 8 + dt) * 256 + l * 4] = y[qt][dt];
      rc[slot * 256 + qt * 64 + l] = rs[qt];
    }
  }
  __syncthreads();
  if (h < 2) {
    const int slot = h * 2 + qs;
    #pragma unroll
    for (int qt = 0; qt < 4; ++qt) {
      #pragma unroll
      for (int dt = 0; dt < 8; ++dt)
        y[qt][dt] += *(const f4*)&yc[slot * 8192 + (qt * 8 + dt) * 256 + l * 4];
      rs[qt] += rc[slot * 256 + qt * 64 + l];
    }
  }
  __syncthreads();
  if (h == 1) {
    #pragma unroll
    for (int qt = 0; qt < 4; ++qt) {
      #pragma unroll
      for (int dt = 0; dt < 8; ++dt)
        *(f4*)&yc[qs * 8192 + (qt * 8 + dt) * 256 + l * 4] = y[qt][dt];
      rc[qs * 256 + qt * 64 + l] = rs[qt];
    }
  }
  __syncthreads();
  if (h == 0) {
    #pragma unroll
    for (int qt = 0; qt < 4; ++qt) {
      #pragma unroll
      for (int dt = 0; dt < 8; ++dt)
        y[qt][dt] += *(const f4*)&yc[qs * 8192 + (qt * 8 + dt) * 256 + l * 4];
      rs[qt] += rc[qs * 256 + qt * 64 + l];
    }
    float* ob = out + (size_t)b * CINT * NN;
    #pragma unroll
    for (int qt = 0; qt < 4; ++qt) {
      f4 rsi;
      #pragma unroll
      for (int r = 0; r < 4; ++r)
        rsi[r] = 1.0f / __shfl(rs[qt], lg * 4 + r, 64);
      #pragma unroll
      for (int dt = 0; dt < 8; ++dt) {
        f4 v = y[qt][dt] * rsi;
        *(float4*)&ob[(size_t)(dt * 16 + lr) * NN + q0 + qt * 16 + lg * 4] = *(float4*)&v;
      }
    }
  }
}

extern "C" void kernel_launch(void* const* d_in, const int* in_sizes, int n_in,
                              void* d_out, int out_size, void* d_ws, size_t ws_size,
                              hipStream_t stream) {
  const float* x   = (const float*)d_in[0];
  const float* wth = (const float*)d_in[1];
  const float* bth = (const float*)d_in[2];
  const float* wph = (const float*)d_in[3];
  const float* bph = (const float*)d_in[4];
  const float* wg  = (const float*)d_in[5];
  const float* bg  = (const float*)d_in[6];
  float* out = (float*)d_out;

  u16* theta = (u16*)d_ws;
  u16* phiT  = theta + (size_t)B_ * NN * CINT;
  u16* gTt   = phiT  + (size_t)B_ * NN * CINT;
  u16* wbf   = gTt   + (size_t)B_ * NN * CINT;

  hipLaunchKernelGGL(prep_kernel, dim3(384), dim3(256), 0, stream, wth, wph, wg, wbf);
  hipLaunchKernelGGL(proj_kernel, dim3(64, 8), dim3(256), 0, stream,
                     x, wbf, bth, bph, bg, theta, phiT, gTt);
  hipLaunchKernelGGL(attn_kernel, dim3(256), dim3(512), 0, stream,
                     theta, phiT, gTt, out);
}